// Round 9
// baseline (203.606 us; speedup 1.0000x reference)
//
#include <hip/hip_runtime.h>
#include <stdint.h>

// ---------- types ----------
typedef float          f32x4  __attribute__((ext_vector_type(4)));
typedef float          f32x16 __attribute__((ext_vector_type(16)));
typedef short          short8 __attribute__((ext_vector_type(8)));
typedef unsigned short us4    __attribute__((ext_vector_type(4)));
typedef unsigned int   u32x4  __attribute__((ext_vector_type(4)));
typedef unsigned long long u64;

#define LOG2E 1.4426950408889634f
#define SCALE_Q (0.125f * LOG2E)   // d^-0.5 * log2(e), folded into q

// f32 -> bf16 round-to-nearest-even
__device__ __forceinline__ unsigned short f2bf(float x) {
  unsigned int u = __float_as_uint(x);
  u += 0x7fffu + ((u >> 16) & 1u);
  return (unsigned short)(u >> 16);
}

// pack two POSITIVE f32 -> u32 of 2 bf16 by truncation (P/l common-mode
// bias cancels in the softmax ratio; validated r6: absmax identical to RNE)
__device__ __forceinline__ unsigned int pk2bf_t(float a, float b) {
  return (__float_as_uint(a) >> 16) | (__float_as_uint(b) & 0xffff0000u);
}

__device__ __forceinline__ f32x4 mfma_bf16(short8 a, short8 b, f32x4 c) {
  return __builtin_amdgcn_mfma_f32_16x16x32_bf16(a, b, c, 0, 0, 0);
}
__device__ __forceinline__ f32x16 mfma32_bf16(short8 a, short8 b, f32x16 c) {
  return __builtin_amdgcn_mfma_f32_32x32x16_bf16(a, b, c, 0, 0, 0);
}

// async global->LDS, 16B per lane. LDS dest = wave-uniform base + lane*16.
__device__ __forceinline__ void lds_load16(void* lds, const void* g) {
  __builtin_amdgcn_global_load_lds(
      (const __attribute__((address_space(1))) unsigned int*)g,
      (__attribute__((address_space(3))) unsigned int*)lds,
      16, 0, 0);
}

// ---------- elementwise f32 -> bf16 (4/thread) ----------
__global__ __launch_bounds__(256) void k_cvt(const float* __restrict__ in,
                                             unsigned short* __restrict__ out,
                                             int n4) {
  int i = blockIdx.x * 256 + threadIdx.x;
  if (i >= n4) return;
  f32x4 v = ((const f32x4*)in)[i];
  us4 o;
  o[0] = f2bf(v[0]); o[1] = f2bf(v[1]); o[2] = f2bf(v[2]); o[3] = f2bf(v[3]);
  ((us4*)out)[i] = o;
}

// ---------- mask -> TRANSPOSED bitmask u64 [64 words][2048 rows] -------------
// Auto-detect element width (int32/f32 vs 1-byte bool) from the first 1KB.
__global__ __launch_bounds__(256) void k_maskbits(const unsigned int* __restrict__ raw,
                                                  u64* __restrict__ bitsT) {
  const int t = threadIdx.x, lane = t & 63, wave = t >> 6;
  u32x4 w0 = ((const u32x4*)raw)[lane];
  bool onebyte = false;
#pragma unroll
  for (int j = 0; j < 4; ++j)
    onebyte |= (w0[j] > 1u && w0[j] != 0x3F800000u);
  onebyte = __any(onebyte);

  const long idx = (long)blockIdx.x * 4 + wave;  // row-major u64-word index
  const long el  = idx * 64 + lane;              // mask element index
  unsigned int v = onebyte ? (unsigned int)((const unsigned char*)raw)[el]
                           : raw[el];
  u64 bal = __ballot(v != 0u);
  if (lane == 0) bitsT[(idx & 63) * 2048 + (idx >> 6)] = bal;
}

// ---------- transpose + convert: in f32 [R][Cc] -> out bf16 [Cc][R] ----------
__global__ __launch_bounds__(256) void k_tcvt(const float* __restrict__ in,
                                              unsigned short* __restrict__ out,
                                              int R, int Cc) {
  __shared__ float tile[32][33];
  int nbc = Cc >> 5;
  int br = blockIdx.x / nbc, bc = blockIdx.x % nbc;
  int r0 = br << 5, c0 = bc << 5;
  int tc = threadIdx.x & 31, tr = threadIdx.x >> 5;
#pragma unroll
  for (int i = 0; i < 4; ++i)
    tile[tr + i * 8][tc] = in[(long)(r0 + tr + i * 8) * Cc + (c0 + tc)];
  __syncthreads();
#pragma unroll
  for (int i = 0; i < 4; ++i)
    out[(long)(c0 + tr + i * 8) * R + (r0 + tc)] = f2bf(tile[tc][tr + i * 8]);
}

// ---------- GEMM: C[Mr,Nc] = A[Mr,K] @ Bt[Nc,K]^T (both bf16, m97 structure) ----
template <int MODE>
__global__ __launch_bounds__(256) void k_gemm_bt(
    const unsigned short* __restrict__ A, const unsigned short* __restrict__ Bt,
    int K, int nbn,
    unsigned short* __restrict__ o_a, unsigned short* __restrict__ o_b,
    float* __restrict__ o_f, const float* __restrict__ bias) {
  __shared__ unsigned short As[128 * 32];
  __shared__ unsigned short Bs[128 * 32];
  const int t = threadIdx.x;
  const int lane = t & 63, wave = t >> 6;
  const int wr = wave >> 1, wc = wave & 1;
  const int rlo = lane & 15, g = lane >> 4;

  const int bm = blockIdx.x / nbn, bn = blockIdx.x % nbn;
  const long row0 = (long)bm * 128, col0 = (long)bn * 128;

  const f32x4 z = {0.f, 0.f, 0.f, 0.f};
  f32x4 acc[4][4];
#pragma unroll
  for (int m = 0; m < 4; ++m)
#pragma unroll
    for (int n = 0; n < 4; ++n) acc[m][n] = z;

  const int srow = t >> 2, skoff = (t & 3) * 8;
  const unsigned short* Ag = A + (row0 + srow) * K + skoff;
  const unsigned short* Bg = Bt + (col0 + srow) * K + skoff;
  char* ldsA = (char*)As + wave * 1024;
  char* ldsB = (char*)Bs + wave * 1024;

  for (int k0 = 0; k0 < K; k0 += 32) {
    lds_load16(ldsA,        Ag + k0);
    lds_load16(ldsA + 4096, Ag + (long)64 * K + k0);
    lds_load16(ldsB,        Bg + k0);
    lds_load16(ldsB + 4096, Bg + (long)64 * K + k0);
    __syncthreads();
    short8 a[4], b[4];
#pragma unroll
    for (int m = 0; m < 4; ++m)
      a[m] = *(const short8*)&As[(wr * 64 + m * 16 + rlo) * 32 + g * 8];
#pragma unroll
    for (int n = 0; n < 4; ++n)
      b[n] = *(const short8*)&Bs[(wc * 64 + n * 16 + rlo) * 32 + g * 8];
#pragma unroll
    for (int m = 0; m < 4; ++m)
#pragma unroll
      for (int n = 0; n < 4; ++n)
        acc[m][n] = mfma_bf16(a[m], b[n], acc[m][n]);
    __syncthreads();
  }

  // C/D layout: col = lane&15, row = (lane>>4)*4 + ri   [m89-verified]
#pragma unroll
  for (int m = 0; m < 4; ++m) {
    const long rb = row0 + wr * 64 + m * 16 + g * 4;
#pragma unroll
    for (int n = 0; n < 4; ++n) {
      const long c = col0 + wc * 64 + n * 16 + rlo;
      if (MODE == 0) {
        const int h = (int)(c >> 6), dd = (int)(c & 63);
#pragma unroll
        for (int ri = 0; ri < 4; ++ri) {
          const long r = rb + ri;
          const long bb = r >> 10, nn = r & 1023;
          o_a[((bb * 16 + h) * 1024 + nn) * 64 + dd] = f2bf(acc[m][n][ri] * SCALE_Q);
        }
      } else if (MODE == 2) {
        const float bv = bias[c];
#pragma unroll
        for (int ri = 0; ri < 4; ++ri)
          o_f[(rb + ri) * 1024 + c] = acc[m][n][ri] + bv;
      } else {
        const long bb = rb >> 12;
        const long mi = rb & 4095;
        if (c < 1024) {
          const int h = (int)(c >> 6), dd = (int)(c & 63);
#pragma unroll
          for (int ri = 0; ri < 4; ++ri)
            o_a[((bb * 16 + h) * 4096 + mi + ri) * 64 + dd] = f2bf(acc[m][n][ri]);
        } else {
          const long c2 = c - 1024;
          const int h = (int)(c2 >> 6), dd = (int)(c2 & 63);
          us4 pk;
#pragma unroll
          for (int ri = 0; ri < 4; ++ri) pk[ri] = f2bf(acc[m][n][ri]);
          *(us4*)&o_b[((bb * 16 + h) * 64 + dd) * 4096 + mi] = pk;
        }
      }
    }
  }
}

// ---------- flash attention: swapped-QK 32x32 MFMA, in-register P -----------
// q [32bh][1024][64] (pre-scaled), k [32bh][4096][64], vT [32bh][64][4096],
// bitsT [64 w][2048 rows].  Grid 1024 = 32bh x 8qt x 4 slices (XCD-swz).
// 4 waves x 32 q-rows = 128 q/block; KVBLK=64 (2 subtiles of 32).
// S^T = mfma32(K,Q): lane q=lane&31 holds P-row slice kv=(r&3)+8(r>>2)+4hi.
// P -> PV A-frags via trunc-pack + permlane32_swap (T12/m214v22 pattern).
// Partials: Apart bf16 [sl][bh][qt][128][64], lpart f32 [sl][bh][qt][128].
__global__ __launch_bounds__(256, 4) void k_attn32(
    const unsigned short* __restrict__ qh, const unsigned short* __restrict__ kh,
    const unsigned short* __restrict__ vt, const u64* __restrict__ bitsT,
    unsigned short* __restrict__ Apart, float* __restrict__ lpart) {
  __shared__ unsigned short Ks[2][64 * 64];   // [buf][kv][d], rows XOR-swizzled
  __shared__ unsigned short Vs[2][64 * 64];   // [buf][d][kv], rows XOR-swizzled

  const int t = threadIdx.x, lane = t & 63, wave = t >> 6;
  const int q32 = lane & 31, hi = lane >> 5;
  const int hi8 = hi * 8, hi4 = hi * 4;

  const int idx = blockIdx.x;
  const int wgid = (idx & 7) * 128 + (idx >> 3);   // 4 bh per XCD
  const int bh = wgid >> 5;
  const int rem = wgid & 31;
  const int qt = rem >> 2, slice = rem & 3;
  const int b = bh >> 4;
  const int q0 = qt * 128;
  const int kt0 = slice * 1024;
  const int qrow = q0 + wave * 32 + q32;           // this lane's q-row

  const unsigned short* kp = kh + (long)bh * 4096 * 64;
  const unsigned short* vp = vt + (long)bh * 64 * 4096;

  // Q B-frags: qb[kt][j] = Q[qrow][kt*16 + hi*8 + j]
  short8 qb[4];
  {
    const unsigned short* qp = qh + ((long)bh * 1024 + qrow) * 64 + hi8;
#pragma unroll
    for (int kt = 0; kt < 4; ++kt) qb[kt] = *(const short8*)(qp + kt * 16);
  }

  f32x16 o0 = {}, o1 = {};
  float l4[4] = {0.f, 0.f, 0.f, 0.f};

  // staging (identical geometry to proven round-4/5 kernels)
  const int srow = t >> 3;
  const int sk = ((t & 7) ^ (srow & 7)) * 8;
  const unsigned short* kg0 = kp + (long)(kt0 + srow) * 64 + sk;
  const unsigned short* kg1 = kp + (long)(kt0 + srow + 32) * 64 + sk;
  const unsigned short* vg0 = vp + (long)srow * 4096 + kt0 + sk;
  const unsigned short* vg1 = vp + (long)(srow + 32) * 4096 + kt0 + sk;

  // transposed bitmask: lane reads its q-row's word; coalesced across lanes
  const u64* bp = bitsT + (long)(slice * 16) * 2048 + (long)b * 1024 + qrow;

  lds_load16((char*)Ks[0] + wave * 1024,        kg0);
  lds_load16((char*)Ks[0] + wave * 1024 + 4096, kg1);
  lds_load16((char*)Vs[0] + wave * 1024,        vg0);
  lds_load16((char*)Vs[0] + wave * 1024 + 4096, vg1);
  __syncthreads();

  for (int ti = 0; ti < 16; ++ti) {
    const int cur = ti & 1;
    const u64 mb = bp[(long)ti * 2048];
    if (ti < 15) {
      const long ko = (long)(ti + 1) * 64 * 64;
      lds_load16((char*)Ks[cur ^ 1] + wave * 1024,        kg0 + ko);
      lds_load16((char*)Ks[cur ^ 1] + wave * 1024 + 4096, kg1 + ko);
      lds_load16((char*)Vs[cur ^ 1] + wave * 1024,        vg0 + (ti + 1) * 64);
      lds_load16((char*)Vs[cur ^ 1] + wave * 1024 + 4096, vg1 + (ti + 1) * 64);
    }

#pragma unroll
    for (int st = 0; st < 2; ++st) {
      const unsigned int w32 = st ? (unsigned int)(mb >> 32) : (unsigned int)mb;
      const unsigned int wsh = w32 >> hi4;

      // ---- S^T = K @ Q : D[kv][q], lane holds 16 kv for q=q32 ----
      f32x16 s = {};
#pragma unroll
      for (int kt = 0; kt < 4; ++kt) {
        const int row = st * 32 + q32;
        const int e = (kt * 16 + hi8) ^ ((row & 7) * 8);
        short8 ka = *(const short8*)&Ks[cur][row * 64 + e];
        s = mfma32_bf16(ka, qb[kt], s);
      }

      // ---- mask + exp2 (log2-domain, no max-track) ----
      float p[16];
#pragma unroll
      for (int r = 0; r < 16; ++r) {
        const int sh = (r & 3) + 8 * (r >> 2);
        const float e2 = __builtin_amdgcn_exp2f(s[r]);
        p[r] = ((wsh >> sh) & 1u) ? 0.f : e2;
        l4[r & 3] += p[r];
      }

      // ---- pack + permlane32_swap -> PV A-frags; O += P @ V ----
#pragma unroll
      for (int kc = 0; kc < 2; ++kc) {
        const unsigned int Aw = pk2bf_t(p[8 * kc + 0], p[8 * kc + 1]);
        const unsigned int Bw = pk2bf_t(p[8 * kc + 2], p[8 * kc + 3]);
        const unsigned int Cw = pk2bf_t(p[8 * kc + 4], p[8 * kc + 5]);
        const unsigned int Dw = pk2bf_t(p[8 * kc + 6], p[8 * kc + 7]);
        u32x4 wv;
#if __has_builtin(__builtin_amdgcn_permlane32_swap)
        // r.x = {Aw(lo-half), Cw(partner-lo)}; r.y = {Aw(partner-hi), Cw(hi-half)}
        auto rAC = __builtin_amdgcn_permlane32_swap(Aw, Cw, false, false);
        auto rBD = __builtin_amdgcn_permlane32_swap(Bw, Dw, false, false);
        wv[0] = rAC[0]; wv[1] = rBD[0]; wv[2] = rAC[1]; wv[3] = rBD[1];
#else
        const unsigned int s0 = hi ? Aw : Cw;
        const unsigned int s1 = hi ? Bw : Dw;
        const unsigned int r0 = (unsigned int)__shfl_xor((int)s0, 32);
        const unsigned int r1 = (unsigned int)__shfl_xor((int)s1, 32);
        wv[0] = hi ? r0 : Aw; wv[1] = hi ? r1 : Bw;
        wv[2] = hi ? Cw : r0; wv[3] = hi ? Dw : r1;
#endif
        const short8 pa = *(const short8*)&wv;
#pragma unroll
        for (int dt = 0; dt < 2; ++dt) {
          const int vrow = dt * 32 + q32;
          const int e = (st * 32 + kc * 16 + hi8) ^ ((vrow & 7) * 8);
          short8 vb = *(const short8*)&Vs[cur][vrow * 64 + e];
          if (dt == 0) o0 = mfma32_bf16(pa, vb, o0);
          else         o1 = mfma32_bf16(pa, vb, o1);
        }
      }
    }
    __syncthreads();  // drains prefetch (vmcnt 0) + protects buffer swap
  }

  // ---- epilogue: partials ----
  const float l_sum = (l4[0] + l4[1]) + (l4[2] + l4[3]);
  const float l_tot = l_sum + __shfl_xor(l_sum, 32);
  const long pbase = (((long)slice * 32 + bh) * 8 + qt) * 128;
  if (hi == 0) lpart[pbase + wave * 32 + q32] = l_tot;
  const long abase = pbase * 64;
#pragma unroll
  for (int r = 0; r < 16; ++r) {
    const int rl = wave * 32 + (r & 3) + 8 * (r >> 2) + hi4;  // C/D row [m74/m101]
    Apart[abase + (long)rl * 64 + q32]      = f2bf(o0[r]);
    Apart[abase + (long)rl * 64 + 32 + q32] = f2bf(o1[r]);
  }
}

// ---------- merge 4 slices: out = (ΣA)/(1+Σl), bf16 -------------------------
__global__ __launch_bounds__(256) void k_merge(const unsigned short* __restrict__ Apart,
                                               const float* __restrict__ lpart,
                                               unsigned short* __restrict__ out) {
  const int t = threadIdx.x;
  const int bh = blockIdx.x >> 3, qt = blockIdx.x & 7;
  const int b = bh >> 4, h = bh & 15;
  const int row = t >> 1, dh = (t & 1) * 32;
  float l = 1.0f;
#pragma unroll
  for (int sl = 0; sl < 4; ++sl)
    l += lpart[(((long)sl * 32 + bh) * 8 + qt) * 128 + row];
  const float inv = 1.0f / l;
  float acc[32];
#pragma unroll
  for (int j = 0; j < 32; ++j) acc[j] = 0.f;
#pragma unroll
  for (int sl = 0; sl < 4; ++sl) {
    const unsigned short* ap =
        Apart + (((long)sl * 32 + bh) * 8 + qt) * 8192 + (long)row * 64 + dh;
#pragma unroll
    for (int c = 0; c < 4; ++c) {
      u32x4 v = *(const u32x4*)(ap + c * 8);   // 8 bf16
#pragma unroll
      for (int j = 0; j < 4; ++j) {
        acc[c * 8 + j * 2]     += __uint_as_float(v[j] << 16);
        acc[c * 8 + j * 2 + 1] += __uint_as_float(v[j] & 0xffff0000u);
      }
    }
  }
  const long ob = ((long)b * 1024 + qt * 128 + row) * 1024 + h * 64 + dh;
#pragma unroll
  for (int c = 0; c < 8; ++c) {
    us4 o;
#pragma unroll
    for (int j = 0; j < 4; ++j) o[j] = f2bf(acc[c * 4 + j] * inv);
    *(us4*)&out[ob + c * 4] = o;
  }
}

// ---------- launcher ----------
extern "C" void kernel_launch(void* const* d_in, const int* in_sizes, int n_in,
                              void* d_out, int out_size, void* d_ws, size_t ws_size,
                              hipStream_t stream) {
  const float* x       = (const float*)d_in[0];
  const float* context = (const float*)d_in[1];
  const unsigned int* maskraw = (const unsigned int*)d_in[2];
  const float* Wq      = (const float*)d_in[3];
  const float* Wkv     = (const float*)d_in[4];
  const float* Wproj   = (const float*)d_in[5];
  const float* bproj   = (const float*)d_in[6];
  float* out = (float*)d_out;

  char* ws = (char*)d_ws;
  const size_t MB = 1024ull * 1024ull;
  // phase-1 tenants:
  unsigned short* ctxb   = (unsigned short*)(ws);              // 16 MB (dead after kv-GEMM)
  unsigned short* xb     = (unsigned short*)(ws + 16 * MB);    //  4 MB (dead after q-GEMM)
  unsigned short* WqT    = (unsigned short*)(ws + 20 * MB);    //  2 MB (dead after q-GEMM)
  unsigned short* WkvT   = (unsigned short*)(ws + 22 * MB);    //  4 MB (dead after kv-GEMM)
  unsigned short* WprojT = (unsigned short*)(ws + 26 * MB);    //  2 MB (live till end)
  unsigned short* qh     = (unsigned short*)(ws + 28 * MB);    //  4 MB
  unsigned short* kh     = (unsigned short*)(ws + 32 * MB);    // 16 MB
  unsigned short* vtr    = (unsigned short*)(ws + 48 * MB);    // 16 MB
  // phase-2 aliases (writer runs after the aliased tenant's last reader):
  unsigned short* Apart   = (unsigned short*)(ws);             // 16 MB over ctxb
  float*          lpart   = (float*)(ws + 16 * MB);            // 512 KB over xb
  u64*            bitsT   = (u64*)(ws + 17 * MB);              // 1 MB over xb
  unsigned short* attnout = (unsigned short*)(ws + 22 * MB);   // 4 MB over WkvT

  // prepass: conversions + weight transposes
  k_cvt<<<dim3(2048), dim3(256), 0, stream>>>(x, xb, 2048 * 1024 / 4);
  k_cvt<<<dim3(8192), dim3(256), 0, stream>>>(context, ctxb, 8192 * 1024 / 4);
  k_tcvt<<<dim3(1024), dim3(256), 0, stream>>>(Wq, WqT, 1024, 1024);
  k_tcvt<<<dim3(2048), dim3(256), 0, stream>>>(Wkv, WkvT, 1024, 2048);
  k_tcvt<<<dim3(1024), dim3(256), 0, stream>>>(Wproj, WprojT, 1024, 1024);

  // projections
  k_gemm_bt<0><<<dim3(16 * 8), dim3(256), 0, stream>>>(xb, WqT, 1024, 8,
                                                       qh, nullptr, nullptr, nullptr);
  k_gemm_bt<1><<<dim3(64 * 16), dim3(256), 0, stream>>>(ctxb, WkvT, 1024, 16,
                                                        kh, vtr, nullptr, nullptr);

  // mask bitmask, transposed (after q-GEMM: reuses xb space)
  k_maskbits<<<dim3(32768), dim3(256), 0, stream>>>(maskraw, bitsT);

  // attention (split-M x4, 32x32 swapped-QK) + merge
  k_attn32<<<dim3(1024), dim3(256), 0, stream>>>(qh, kh, vtr, bitsT, Apart, lpart);
  k_merge<<<dim3(256), dim3(256), 0, stream>>>(Apart, lpart, attnout);

  // output projection (+bias, f32 out)
  k_gemm_bt<2><<<dim3(16 * 8), dim3(256), 0, stream>>>(attnout, WprojT, 1024, 8,
                                                       nullptr, nullptr, out, bproj);
}

// Round 10
// 184.420 us; speedup vs baseline: 1.1040x; 1.1040x over previous
//
#include <hip/hip_runtime.h>
#include <stdint.h>

// ---------- types ----------
typedef float          f32x4  __attribute__((ext_vector_type(4)));
typedef float          f32x16 __attribute__((ext_vector_type(16)));
typedef short          short8 __attribute__((ext_vector_type(8)));
typedef unsigned short us4    __attribute__((ext_vector_type(4)));
typedef unsigned int   u32x4  __attribute__((ext_vector_type(4)));
typedef unsigned long long u64;

#define LOG2E 1.4426950408889634f
#define SCALE_Q (0.125f * LOG2E)   // d^-0.5 * log2(e), folded into q

// f32 -> bf16 round-to-nearest-even
__device__ __forceinline__ unsigned short f2bf(float x) {
  unsigned int u = __float_as_uint(x);
  u += 0x7fffu + ((u >> 16) & 1u);
  return (unsigned short)(u >> 16);
}

// pack two POSITIVE f32 -> u32 of 2 bf16 by truncation (P/l common-mode
// bias cancels in the softmax ratio; validated r6: absmax identical to RNE)
__device__ __forceinline__ unsigned int pk2bf_t(float a, float b) {
  return (__float_as_uint(a) >> 16) | (__float_as_uint(b) & 0xffff0000u);
}

__device__ __forceinline__ f32x4 mfma_bf16(short8 a, short8 b, f32x4 c) {
  return __builtin_amdgcn_mfma_f32_16x16x32_bf16(a, b, c, 0, 0, 0);
}
__device__ __forceinline__ f32x16 mfma32_bf16(short8 a, short8 b, f32x16 c) {
  return __builtin_amdgcn_mfma_f32_32x32x16_bf16(a, b, c, 0, 0, 0);
}

// async global->LDS, 16B per lane. LDS dest = wave-uniform base + lane*16.
__device__ __forceinline__ void lds_load16(void* lds, const void* g) {
  __builtin_amdgcn_global_load_lds(
      (const __attribute__((address_space(1))) unsigned int*)g,
      (__attribute__((address_space(3))) unsigned int*)lds,
      16, 0, 0);
}

// ---------- elementwise f32 -> bf16 (4/thread) ----------
__global__ __launch_bounds__(256) void k_cvt(const float* __restrict__ in,
                                             unsigned short* __restrict__ out,
                                             int n4) {
  int i = blockIdx.x * 256 + threadIdx.x;
  if (i >= n4) return;
  f32x4 v = ((const f32x4*)in)[i];
  us4 o;
  o[0] = f2bf(v[0]); o[1] = f2bf(v[1]); o[2] = f2bf(v[2]); o[3] = f2bf(v[3]);
  ((us4*)out)[i] = o;
}

// ---------- mask -> TRANSPOSED bitmask u64 [64 words][2048 rows] -------------
// Auto-detect element width (int32/f32 vs 1-byte bool) from the first 1KB.
__global__ __launch_bounds__(256) void k_maskbits(const unsigned int* __restrict__ raw,
                                                  u64* __restrict__ bitsT) {
  const int t = threadIdx.x, lane = t & 63, wave = t >> 6;
  u32x4 w0 = ((const u32x4*)raw)[lane];
  bool onebyte = false;
#pragma unroll
  for (int j = 0; j < 4; ++j)
    onebyte |= (w0[j] > 1u && w0[j] != 0x3F800000u);
  onebyte = __any(onebyte);

  const long idx = (long)blockIdx.x * 4 + wave;  // row-major u64-word index
  const long el  = idx * 64 + lane;              // mask element index
  unsigned int v = onebyte ? (unsigned int)((const unsigned char*)raw)[el]
                           : raw[el];
  u64 bal = __ballot(v != 0u);
  if (lane == 0) bitsT[(idx & 63) * 2048 + (idx >> 6)] = bal;
}

// ---------- transpose + convert: in f32 [R][Cc] -> out bf16 [Cc][R] ----------
__global__ __launch_bounds__(256) void k_tcvt(const float* __restrict__ in,
                                              unsigned short* __restrict__ out,
                                              int R, int Cc) {
  __shared__ float tile[32][33];
  int nbc = Cc >> 5;
  int br = blockIdx.x / nbc, bc = blockIdx.x % nbc;
  int r0 = br << 5, c0 = bc << 5;
  int tc = threadIdx.x & 31, tr = threadIdx.x >> 5;
#pragma unroll
  for (int i = 0; i < 4; ++i)
    tile[tr + i * 8][tc] = in[(long)(r0 + tr + i * 8) * Cc + (c0 + tc)];
  __syncthreads();
#pragma unroll
  for (int i = 0; i < 4; ++i)
    out[(long)(c0 + tr + i * 8) * R + (r0 + tc)] = f2bf(tile[tc][tr + i * 8]);
}

// ---------- GEMM: C[Mr,Nc] = A[Mr,K] @ Bt[Nc,K]^T (bf16, 2-phase prefetch) ----
// TM=128: 4 waves in 2x2, acc[4][4] (proven m97 layout).
// TM=64 : 4 waves in 1x4 (wc=wave), acc[4][2] — doubles block count for the
//         grid-starved q/out projections (128 blocks -> 256 = 1/CU).
// K-loop: T3-minimum double-buffered prefetch (stage t+1 before compute t,
// ONE barrier per step; its implicit vmcnt(0) drains the prefetch) — the
// structure proven in k_attn32 rounds 4-9.
// MODE 0: q-proj   -> o_a = q   [B,H,N,64] bf16, scaled by SCALE_Q
// MODE 1: kv-proj  -> o_a = k   [B,H,M,64] bf16 ; o_b = vT [B,H,64,M] bf16
// MODE 2: out-proj -> o_f = out [B,N,C] f32 (+bias)
template <int MODE, int TM>
__global__ __launch_bounds__(256) void k_gemm_bt(
    const unsigned short* __restrict__ A, const unsigned short* __restrict__ Bt,
    int K, int nbn,
    unsigned short* __restrict__ o_a, unsigned short* __restrict__ o_b,
    float* __restrict__ o_f, const float* __restrict__ bias) {
  __shared__ unsigned short As[2][TM * 32];
  __shared__ unsigned short Bs[2][128 * 32];
  constexpr int NF = (TM == 128) ? 4 : 2;
  const int t = threadIdx.x;
  const int lane = t & 63, wave = t >> 6;
  const int wr = wave >> 1, wc = wave & 1;
  const int rlo = lane & 15, g = lane >> 4;

  // bijective XCD swizzle (grid % 8 == 0 for all three launches)
  const int cpx = (int)gridDim.x >> 3;
  const int wg = (blockIdx.x & 7) * cpx + (blockIdx.x >> 3);
  const int bm = wg / nbn, bn = wg % nbn;
  const long row0 = (long)bm * TM, col0 = (long)bn * 128;

  const f32x4 z = {0.f, 0.f, 0.f, 0.f};
  f32x4 acc[4][NF];
#pragma unroll
  for (int m = 0; m < 4; ++m)
#pragma unroll
    for (int n = 0; n < NF; ++n) acc[m][n] = z;

  const int srow = t >> 2, skoff = (t & 3) * 8;
  const unsigned short* Ag = A + (row0 + srow) * K + skoff;
  const unsigned short* Bg = Bt + (col0 + srow) * K + skoff;

  auto stage = [&](int buf, int k0) {
    char* ldsA = (char*)As[buf] + wave * 1024;
    char* ldsB = (char*)Bs[buf] + wave * 1024;
    lds_load16(ldsA, Ag + k0);
    if (TM == 128) lds_load16(ldsA + 4096, Ag + (long)64 * K + k0);
    lds_load16(ldsB, Bg + k0);
    lds_load16(ldsB + 4096, Bg + (long)64 * K + k0);
  };

  stage(0, 0);
  __syncthreads();
  const int nk = K >> 5;
  for (int ti = 0; ti < nk; ++ti) {
    const int cur = ti & 1;
    if (ti < nk - 1) stage(cur ^ 1, (ti + 1) * 32);  // prefetch next tile
    short8 a[4], b[NF];
#pragma unroll
    for (int m = 0; m < 4; ++m) {
      const int row = (TM == 128) ? (wr * 64 + m * 16 + rlo) : (m * 16 + rlo);
      a[m] = *(const short8*)&As[cur][row * 32 + g * 8];
    }
#pragma unroll
    for (int n = 0; n < NF; ++n) {
      const int row = (TM == 128) ? (wc * 64 + n * 16 + rlo) : (wave * 32 + n * 16 + rlo);
      b[n] = *(const short8*)&Bs[cur][row * 32 + g * 8];
    }
#pragma unroll
    for (int m = 0; m < 4; ++m)
#pragma unroll
      for (int n = 0; n < NF; ++n)
        acc[m][n] = mfma_bf16(a[m], b[n], acc[m][n]);
    __syncthreads();  // drains prefetch (vmcnt 0) + protects buffer swap
  }

  // C/D layout: col = lane&15, row = (lane>>4)*4 + ri   [m89-verified]
#pragma unroll
  for (int m = 0; m < 4; ++m) {
    const long rb = row0 + ((TM == 128) ? wr * 64 : 0) + m * 16 + g * 4;
#pragma unroll
    for (int n = 0; n < NF; ++n) {
      const long c = col0 + ((TM == 128) ? wc * 64 : wave * 32) + n * 16 + rlo;
      if (MODE == 0) {
        const int h = (int)(c >> 6), dd = (int)(c & 63);
#pragma unroll
        for (int ri = 0; ri < 4; ++ri) {
          const long r = rb + ri;
          const long bb = r >> 10, nn = r & 1023;
          o_a[((bb * 16 + h) * 1024 + nn) * 64 + dd] = f2bf(acc[m][n][ri] * SCALE_Q);
        }
      } else if (MODE == 2) {
        const float bv = bias[c];
#pragma unroll
        for (int ri = 0; ri < 4; ++ri)
          o_f[(rb + ri) * 1024 + c] = acc[m][n][ri] + bv;
      } else {
        const long bb = rb >> 12;
        const long mi = rb & 4095;
        if (c < 1024) {
          const int h = (int)(c >> 6), dd = (int)(c & 63);
#pragma unroll
          for (int ri = 0; ri < 4; ++ri)
            o_a[((bb * 16 + h) * 4096 + mi + ri) * 64 + dd] = f2bf(acc[m][n][ri]);
        } else {
          const long c2 = c - 1024;
          const int h = (int)(c2 >> 6), dd = (int)(c2 & 63);
          us4 pk;
#pragma unroll
          for (int ri = 0; ri < 4; ++ri) pk[ri] = f2bf(acc[m][n][ri]);
          *(us4*)&o_b[((bb * 16 + h) * 64 + dd) * 4096 + mi] = pk;
        }
      }
    }
  }
}

// ---------- flash attention: swapped-QK 32x32 MFMA, in-register P -----------
// (unchanged from round 9: 204 µs total, attn below top-5)
__global__ __launch_bounds__(256, 4) void k_attn32(
    const unsigned short* __restrict__ qh, const unsigned short* __restrict__ kh,
    const unsigned short* __restrict__ vt, const u64* __restrict__ bitsT,
    unsigned short* __restrict__ Apart, float* __restrict__ lpart) {
  __shared__ unsigned short Ks[2][64 * 64];   // [buf][kv][d], rows XOR-swizzled
  __shared__ unsigned short Vs[2][64 * 64];   // [buf][d][kv], rows XOR-swizzled

  const int t = threadIdx.x, lane = t & 63, wave = t >> 6;
  const int q32 = lane & 31, hi = lane >> 5;
  const int hi8 = hi * 8, hi4 = hi * 4;

  const int idx = blockIdx.x;
  const int wgid = (idx & 7) * 128 + (idx >> 3);   // 4 bh per XCD
  const int bh = wgid >> 5;
  const int rem = wgid & 31;
  const int qt = rem >> 2, slice = rem & 3;
  const int b = bh >> 4;
  const int q0 = qt * 128;
  const int kt0 = slice * 1024;
  const int qrow = q0 + wave * 32 + q32;           // this lane's q-row

  const unsigned short* kp = kh + (long)bh * 4096 * 64;
  const unsigned short* vp = vt + (long)bh * 64 * 4096;

  short8 qb[4];
  {
    const unsigned short* qp = qh + ((long)bh * 1024 + qrow) * 64 + hi8;
#pragma unroll
    for (int kt = 0; kt < 4; ++kt) qb[kt] = *(const short8*)(qp + kt * 16);
  }

  f32x16 o0 = {}, o1 = {};
  float l4[4] = {0.f, 0.f, 0.f, 0.f};

  const int srow = t >> 3;
  const int sk = ((t & 7) ^ (srow & 7)) * 8;
  const unsigned short* kg0 = kp + (long)(kt0 + srow) * 64 + sk;
  const unsigned short* kg1 = kp + (long)(kt0 + srow + 32) * 64 + sk;
  const unsigned short* vg0 = vp + (long)srow * 4096 + kt0 + sk;
  const unsigned short* vg1 = vp + (long)(srow + 32) * 4096 + kt0 + sk;

  const u64* bp = bitsT + (long)(slice * 16) * 2048 + (long)b * 1024 + qrow;

  lds_load16((char*)Ks[0] + wave * 1024,        kg0);
  lds_load16((char*)Ks[0] + wave * 1024 + 4096, kg1);
  lds_load16((char*)Vs[0] + wave * 1024,        vg0);
  lds_load16((char*)Vs[0] + wave * 1024 + 4096, vg1);
  __syncthreads();

  for (int ti = 0; ti < 16; ++ti) {
    const int cur = ti & 1;
    const u64 mb = bp[(long)ti * 2048];
    if (ti < 15) {
      const long ko = (long)(ti + 1) * 64 * 64;
      lds_load16((char*)Ks[cur ^ 1] + wave * 1024,        kg0 + ko);
      lds_load16((char*)Ks[cur ^ 1] + wave * 1024 + 4096, kg1 + ko);
      lds_load16((char*)Vs[cur ^ 1] + wave * 1024,        vg0 + (ti + 1) * 64);
      lds_load16((char*)Vs[cur ^ 1] + wave * 1024 + 4096, vg1 + (ti + 1) * 64);
    }

#pragma unroll
    for (int st = 0; st < 2; ++st) {
      const unsigned int w32 = st ? (unsigned int)(mb >> 32) : (unsigned int)mb;
      const unsigned int wsh = w32 >> hi4;

      f32x16 s = {};
#pragma unroll
      for (int kt = 0; kt < 4; ++kt) {
        const int row = st * 32 + q32;
        const int e = (kt * 16 + hi8) ^ ((row & 7) * 8);
        short8 ka = *(const short8*)&Ks[cur][row * 64 + e];
        s = mfma32_bf16(ka, qb[kt], s);
      }

      float p[16];
#pragma unroll
      for (int r = 0; r < 16; ++r) {
        const int sh = (r & 3) + 8 * (r >> 2);
        const float e2 = __builtin_amdgcn_exp2f(s[r]);
        p[r] = ((wsh >> sh) & 1u) ? 0.f : e2;
        l4[r & 3] += p[r];
      }

#pragma unroll
      for (int kc = 0; kc < 2; ++kc) {
        const unsigned int Aw = pk2bf_t(p[8 * kc + 0], p[8 * kc + 1]);
        const unsigned int Bw = pk2bf_t(p[8 * kc + 2], p[8 * kc + 3]);
        const unsigned int Cw = pk2bf_t(p[8 * kc + 4], p[8 * kc + 5]);
        const unsigned int Dw = pk2bf_t(p[8 * kc + 6], p[8 * kc + 7]);
        u32x4 wv;
#if __has_builtin(__builtin_amdgcn_permlane32_swap)
        auto rAC = __builtin_amdgcn_permlane32_swap(Aw, Cw, false, false);
        auto rBD = __builtin_amdgcn_permlane32_swap(Bw, Dw, false, false);
        wv[0] = rAC[0]; wv[1] = rBD[0]; wv[2] = rAC[1]; wv[3] = rBD[1];
#else
        const unsigned int s0 = hi ? Aw : Cw;
        const unsigned int s1 = hi ? Bw : Dw;
        const unsigned int r0 = (unsigned int)__shfl_xor((int)s0, 32);
        const unsigned int r1 = (unsigned int)__shfl_xor((int)s1, 32);
        wv[0] = hi ? r0 : Aw; wv[1] = hi ? r1 : Bw;
        wv[2] = hi ? Cw : r0; wv[3] = hi ? Dw : r1;
#endif
        const short8 pa = *(const short8*)&wv;
#pragma unroll
        for (int dt = 0; dt < 2; ++dt) {
          const int vrow = dt * 32 + q32;
          const int e = (st * 32 + kc * 16 + hi8) ^ ((vrow & 7) * 8);
          short8 vb = *(const short8*)&Vs[cur][vrow * 64 + e];
          if (dt == 0) o0 = mfma32_bf16(pa, vb, o0);
          else         o1 = mfma32_bf16(pa, vb, o1);
        }
      }
    }
    __syncthreads();  // drains prefetch (vmcnt 0) + protects buffer swap
  }

  // ---- epilogue: partials ----
  const float l_sum = (l4[0] + l4[1]) + (l4[2] + l4[3]);
  const float l_tot = l_sum + __shfl_xor(l_sum, 32);
  const long pbase = (((long)slice * 32 + bh) * 8 + qt) * 128;
  if (hi == 0) lpart[pbase + wave * 32 + q32] = l_tot;
  const long abase = pbase * 64;
#pragma unroll
  for (int r = 0; r < 16; ++r) {
    const int rl = wave * 32 + (r & 3) + 8 * (r >> 2) + hi4;  // C/D row [m74/m101]
    Apart[abase + (long)rl * 64 + q32]      = f2bf(o0[r]);
    Apart[abase + (long)rl * 64 + 32 + q32] = f2bf(o1[r]);
  }
}

// ---------- merge 4 slices: out = (ΣA)/(1+Σl), bf16 -------------------------
__global__ __launch_bounds__(256) void k_merge(const unsigned short* __restrict__ Apart,
                                               const float* __restrict__ lpart,
                                               unsigned short* __restrict__ out) {
  const int t = threadIdx.x;
  const int bh = blockIdx.x >> 3, qt = blockIdx.x & 7;
  const int b = bh >> 4, h = bh & 15;
  const int row = t >> 1, dh = (t & 1) * 32;
  float l = 1.0f;
#pragma unroll
  for (int sl = 0; sl < 4; ++sl)
    l += lpart[(((long)sl * 32 + bh) * 8 + qt) * 128 + row];
  const float inv = 1.0f / l;
  float acc[32];
#pragma unroll
  for (int j = 0; j < 32; ++j) acc[j] = 0.f;
#pragma unroll
  for (int sl = 0; sl < 4; ++sl) {
    const unsigned short* ap =
        Apart + (((long)sl * 32 + bh) * 8 + qt) * 8192 + (long)row * 64 + dh;
#pragma unroll
    for (int c = 0; c < 4; ++c) {
      u32x4 v = *(const u32x4*)(ap + c * 8);   // 8 bf16
#pragma unroll
      for (int j = 0; j < 4; ++j) {
        acc[c * 8 + j * 2]     += __uint_as_float(v[j] << 16);
        acc[c * 8 + j * 2 + 1] += __uint_as_float(v[j] & 0xffff0000u);
      }
    }
  }
  const long ob = ((long)b * 1024 + qt * 128 + row) * 1024 + h * 64 + dh;
#pragma unroll
  for (int c = 0; c < 8; ++c) {
    us4 o;
#pragma unroll
    for (int j = 0; j < 4; ++j) o[j] = f2bf(acc[c * 4 + j] * inv);
    *(us4*)&out[ob + c * 4] = o;
  }
}

// ---------- launcher ----------
extern "C" void kernel_launch(void* const* d_in, const int* in_sizes, int n_in,
                              void* d_out, int out_size, void* d_ws, size_t ws_size,
                              hipStream_t stream) {
  const float* x       = (const float*)d_in[0];
  const float* context = (const float*)d_in[1];
  const unsigned int* maskraw = (const unsigned int*)d_in[2];
  const float* Wq      = (const float*)d_in[3];
  const float* Wkv     = (const float*)d_in[4];
  const float* Wproj   = (const float*)d_in[5];
  const float* bproj   = (const float*)d_in[6];
  float* out = (float*)d_out;

  char* ws = (char*)d_ws;
  const size_t MB = 1024ull * 1024ull;
  // phase-1 tenants:
  unsigned short* ctxb   = (unsigned short*)(ws);              // 16 MB (dead after kv-GEMM)
  unsigned short* xb     = (unsigned short*)(ws + 16 * MB);    //  4 MB (dead after q-GEMM)
  unsigned short* WqT    = (unsigned short*)(ws + 20 * MB);    //  2 MB (dead after q-GEMM)
  unsigned short* WkvT   = (unsigned short*)(ws + 22 * MB);    //  4 MB (dead after kv-GEMM)
  unsigned short* WprojT = (unsigned short*)(ws + 26 * MB);    //  2 MB (live till end)
  unsigned short* qh     = (unsigned short*)(ws + 28 * MB);    //  4 MB
  unsigned short* kh     = (unsigned short*)(ws + 32 * MB);    // 16 MB
  unsigned short* vtr    = (unsigned short*)(ws + 48 * MB);    // 16 MB
  // phase-2 aliases (writer runs after the aliased tenant's last reader):
  unsigned short* Apart   = (unsigned short*)(ws);             // 16 MB over ctxb
  float*          lpart   = (float*)(ws + 16 * MB);            // 512 KB over xb
  u64*            bitsT   = (u64*)(ws + 17 * MB);              // 1 MB over xb
  unsigned short* attnout = (unsigned short*)(ws + 22 * MB);   // 4 MB over WkvT

  // prepass: conversions + weight transposes
  k_cvt<<<dim3(2048), dim3(256), 0, stream>>>(x, xb, 2048 * 1024 / 4);
  k_cvt<<<dim3(8192), dim3(256), 0, stream>>>(context, ctxb, 8192 * 1024 / 4);
  k_tcvt<<<dim3(1024), dim3(256), 0, stream>>>(Wq, WqT, 1024, 1024);
  k_tcvt<<<dim3(2048), dim3(256), 0, stream>>>(Wkv, WkvT, 1024, 2048);
  k_tcvt<<<dim3(1024), dim3(256), 0, stream>>>(Wproj, WprojT, 1024, 1024);

  // projections (q/out: 64-row tiles -> 256 blocks = 1/CU; kv: proven 128^2)
  k_gemm_bt<0, 64><<<dim3(32 * 8), dim3(256), 0, stream>>>(xb, WqT, 1024, 8,
                                                       qh, nullptr, nullptr, nullptr);
  k_gemm_bt<1, 128><<<dim3(64 * 16), dim3(256), 0, stream>>>(ctxb, WkvT, 1024, 16,
                                                        kh, vtr, nullptr, nullptr);

  // mask bitmask, transposed (after q-GEMM: reuses xb space)
  k_maskbits<<<dim3(32768), dim3(256), 0, stream>>>(maskraw, bitsT);

  // attention (split-M x4, 32x32 swapped-QK) + merge
  k_attn32<<<dim3(1024), dim3(256), 0, stream>>>(qh, kh, vtr, bitsT, Apart, lpart);
  k_merge<<<dim3(256), dim3(256), 0, stream>>>(Apart, lpart, attnout);

  // output projection (+bias, f32 out)
  k_gemm_bt<2, 64><<<dim3(32 * 8), dim3(256), 0, stream>>>(attnout, WprojT, 1024, 8,
                                                       nullptr, nullptr, out, bproj);
}